// Round 4
// baseline (295.872 us; speedup 1.0000x reference)
//
#include <hip/hip_runtime.h>
#include <math.h>

// Mean over B rows of KL divergence between diagonal Gaussians.
// B=65536, N=256. out = 0.5 * (sum_all(term)/B - N), where
// term = log(s2)-log(s1) + s1/s2 + (mask*(mu2-mu1))^2/s2.
//
// R1-R3 post-mortem: ~110us regardless of source-level load hoisting; the
// backend sinks loads to uses (VGPR stuck at 36), so each wave has ~2 loads
// in flight. Total ingress 3.04 TB/s == copy-ubench read rate (3.15 TB/s).
// R4 decisive test: global_load_lds async staging (no VGPR dest -> scheduler
// cannot sink), 2-deep per-wave pipeline, s_waitcnt vmcnt(5), no barriers
// (each wave consumes only its own LDS region). 10KB in flight per wave.

constexpr int B_ROWS = 65536;
constexpr int N_COLS = 256;
constexpr int TOTAL4 = (B_ROWS * N_COLS) / 4;   // 4,194,304 float4s per array
constexpr int GRID1  = 1024;                    // 4 blocks/CU (LDS-limited), all resident
constexpr int BLOCK  = 256;
constexpr int WAVES  = BLOCK / 64;
constexpr int PER_BLOCK4 = TOTAL4 / GRID1;      // 4096 float4s per array per block
constexpr int STEPS  = PER_BLOCK4 / BLOCK;      // 16 pipeline steps

// s_waitcnt imm: vmcnt[3:0], expcnt[6:4]=7 (don't care), lgkmcnt[11:8]=15 (don't care)
#define WAITCNT_VM(n) __builtin_amdgcn_s_waitcnt(0xF70 | (n))

__device__ __forceinline__ void stage_wave(const float4* __restrict__ g, float4* l) {
    // Per-lane global addr g (+lane folded in by caller); LDS dest is
    // wave-uniform base, HW scatters lane i to base + i*16.
    __builtin_amdgcn_global_load_lds((const __attribute__((address_space(1))) void*)g,
                                     (__attribute__((address_space(3))) void*)l,
                                     16, 0, 0);
}

__device__ __forceinline__ float kl_term(float m1, float m2, float s1, float s2, float mk) {
    m1 = __builtin_isnan(m1) ? 0.0f : m1;      // nan_to_num(mu1)
    float d  = mk * (m2 - m1);
    float r2 = __builtin_amdgcn_rcpf(s2);      // 2% tolerance; approx ok
    float lg = 0.69314718055994531f * (__log2f(s2) - __log2f(s1));
    return lg + (s1 + d * d) * r2;
}

__device__ __forceinline__ float kl4(float4 a, float4 b, float4 p, float4 q, float4 m) {
    return kl_term(a.x, b.x, p.x, q.x, m.x)
         + kl_term(a.y, b.y, p.y, q.y, m.y)
         + kl_term(a.z, b.z, p.z, q.z, m.z)
         + kl_term(a.w, b.w, p.w, q.w, m.w);
}

__global__ __launch_bounds__(BLOCK) void kl_partial_kernel(
    const float4* __restrict__ mu1, const float4* __restrict__ mu2,
    const float4* __restrict__ s1,  const float4* __restrict__ s2,
    const float4* __restrict__ mask, float* __restrict__ partials)
{
    // [buf 2][array 5][wave 4][lane 64] float4 = 40 KiB
    __shared__ float4 smem[2 * 5 * WAVES * 64];
    const int lane = threadIdx.x & 63;
    const int wv   = threadIdx.x >> 6;
    const int base = blockIdx.x * PER_BLOCK4;

    auto lds_base = [&](int buf, int arr) -> float4* {
        return &smem[((buf * 5 + arr) * WAVES + wv) * 64];
    };
    auto stage_step = [&](int s, int buf) {
        const int gi = base + s * BLOCK + wv * 64 + lane;
        stage_wave(mu1  + gi, lds_base(buf, 0));
        stage_wave(mu2  + gi, lds_base(buf, 1));
        stage_wave(s1   + gi, lds_base(buf, 2));
        stage_wave(s2   + gi, lds_base(buf, 3));
        stage_wave(mask + gi, lds_base(buf, 4));
    };

    float acc = 0.0f;
    stage_step(0, 0);
    for (int s = 0; s < STEPS; ++s) {
        const int buf = s & 1;
        // Fence: prior step's ds_reads + uses may not drift below the next
        // stage (which overwrites the buffer they read two steps back).
        __builtin_amdgcn_sched_barrier(0);
        if (s + 1 < STEPS) {
            stage_step(s + 1, buf ^ 1);
            WAITCNT_VM(5);   // wait for current buf's 5 loads; next 5 stay in flight
        } else {
            WAITCNT_VM(0);
        }
        __builtin_amdgcn_sched_barrier(0);
        float4 a = lds_base(buf, 0)[lane];
        float4 b = lds_base(buf, 1)[lane];
        float4 p = lds_base(buf, 2)[lane];
        float4 q = lds_base(buf, 3)[lane];
        float4 m = lds_base(buf, 4)[lane];
        acc += kl4(a, b, p, q, m);
    }

    // wave-64 reduction, then cross-wave via LDS (reuse smem area, post-loop)
    #pragma unroll
    for (int off = 32; off > 0; off >>= 1) acc += __shfl_down(acc, off, 64);
    __shared__ float wsum[WAVES];
    if (lane == 0) wsum[wv] = acc;
    __syncthreads();
    if (threadIdx.x == 0) {
        float sblk = 0.0f;
        #pragma unroll
        for (int w = 0; w < WAVES; ++w) sblk += wsum[w];
        partials[blockIdx.x] = sblk;  // unconditional write every launch (poison-safe)
    }
}

__global__ __launch_bounds__(BLOCK) void kl_final_kernel(
    const float* __restrict__ partials, float* __restrict__ out)
{
    double acc = 0.0;
    for (int i = threadIdx.x; i < GRID1; i += BLOCK) acc += (double)partials[i];
    #pragma unroll
    for (int off = 32; off > 0; off >>= 1) acc += __shfl_down(acc, off, 64);
    __shared__ double wsum[BLOCK / 64];
    const int lane = threadIdx.x & 63;
    const int wv   = threadIdx.x >> 6;
    if (lane == 0) wsum[wv] = acc;
    __syncthreads();
    if (threadIdx.x == 0) {
        double s = 0.0;
        #pragma unroll
        for (int w = 0; w < BLOCK / 64; ++w) s += wsum[w];
        out[0] = (float)(0.5 * s / (double)B_ROWS - 0.5 * (double)N_COLS);
    }
}

extern "C" void kernel_launch(void* const* d_in, const int* in_sizes, int n_in,
                              void* d_out, int out_size, void* d_ws, size_t ws_size,
                              hipStream_t stream) {
    const float4* mu1  = (const float4*)d_in[0];
    const float4* mu2  = (const float4*)d_in[1];
    const float4* sg1  = (const float4*)d_in[2];
    const float4* sg2  = (const float4*)d_in[3];
    const float4* mask = (const float4*)d_in[4];
    float* partials = (float*)d_ws;  // GRID1 floats = 4 KiB scratch
    float* out = (float*)d_out;

    kl_partial_kernel<<<GRID1, BLOCK, 0, stream>>>(mu1, mu2, sg1, sg2, mask, partials);
    kl_final_kernel<<<1, BLOCK, 0, stream>>>(partials, out);
}

// Round 5
// 290.773 us; speedup vs baseline: 1.0175x; 1.0175x over previous
//
#include <hip/hip_runtime.h>
#include <math.h>

// Mean over B rows of KL divergence between diagonal Gaussians.
// B=65536, N=256. out = 0.5 * (sum_all(term)/B - N), where
// term = log(s2)-log(s1) + s1/s2 + (mask*(mu2-mu1))^2/s2.
//
// FINAL (R5 = revert to R3, the best-measured variant: 110.3us kernel).
//
// Session findings (R1-R4):
//  - Latency/MLP theory falsified: async global_load_lds with 80KB/CU in
//    flight (13x Little's-law for 6.3TB/s) moved nothing (R4, 118us).
//  - Ceiling is a ~3.1 TB/s read-delivery path (cache->CU): L3-warm
//    replays (FETCH~0) run identical time to HBM-cold; matches the m13
//    copy ubench read stream (6.29 TB/s bidirectional = 3.15 TB/s read).
//  - FETCH_SIZE == ideal input bytes (no over-fetch); VALU 6%; bytes are
//    irreducible (5 x fp32 x 16.7M). Kernel sits at ~97% of the
//    demonstrated read-path ceiling => roofline.

constexpr int B_ROWS = 65536;
constexpr int N_COLS = 256;
constexpr int TOTAL4 = (B_ROWS * N_COLS) / 4;  // 4,194,304 float4s per array
constexpr int GRID1  = 4096;
constexpr int BLOCK  = 256;
constexpr int ITERS  = TOTAL4 / (GRID1 * BLOCK);  // = 4 float4s/thread/array

__device__ __forceinline__ float kl_term(float m1, float m2, float s1, float s2, float mk) {
    m1 = __builtin_isnan(m1) ? 0.0f : m1;      // nan_to_num(mu1)
    float d  = mk * (m2 - m1);
    float r2 = __builtin_amdgcn_rcpf(s2);      // tolerance is 2%; approx ok
    float lg = 0.69314718055994531f * (__log2f(s2) - __log2f(s1));
    return lg + (s1 + d * d) * r2;
}

__device__ __forceinline__ float kl4(float4 a, float4 b, float4 p, float4 q, float4 m) {
    return kl_term(a.x, b.x, p.x, q.x, m.x)
         + kl_term(a.y, b.y, p.y, q.y, m.y)
         + kl_term(a.z, b.z, p.z, q.z, m.z)
         + kl_term(a.w, b.w, p.w, q.w, m.w);
}

__global__ __launch_bounds__(BLOCK, 4) void kl_partial_kernel(
    const float4* __restrict__ mu1, const float4* __restrict__ mu2,
    const float4* __restrict__ s1,  const float4* __restrict__ s2,
    const float4* __restrict__ mask, float* __restrict__ partials)
{
    const int base = blockIdx.x * (BLOCK * ITERS) + threadIdx.x;

    float4 A[ITERS], Bv[ITERS], P[ITERS], Q[ITERS], M[ITERS];
    #pragma unroll
    for (int k = 0; k < ITERS; ++k) A[k]  = mu1[base + k * BLOCK];
    #pragma unroll
    for (int k = 0; k < ITERS; ++k) Bv[k] = mu2[base + k * BLOCK];
    #pragma unroll
    for (int k = 0; k < ITERS; ++k) P[k]  = s1[base + k * BLOCK];
    #pragma unroll
    for (int k = 0; k < ITERS; ++k) Q[k]  = s2[base + k * BLOCK];
    #pragma unroll
    for (int k = 0; k < ITERS; ++k) M[k]  = mask[base + k * BLOCK];

    float acc0 = 0.0f, acc1 = 0.0f;
    #pragma unroll
    for (int k = 0; k < ITERS; k += 2) {
        acc0 += kl4(A[k],     Bv[k],     P[k],     Q[k],     M[k]);
        acc1 += kl4(A[k + 1], Bv[k + 1], P[k + 1], Q[k + 1], M[k + 1]);
    }
    float acc = acc0 + acc1;

    // wave-64 reduction
    #pragma unroll
    for (int off = 32; off > 0; off >>= 1) acc += __shfl_down(acc, off, 64);
    __shared__ float wsum[BLOCK / 64];
    const int lane = threadIdx.x & 63;
    const int wv   = threadIdx.x >> 6;
    if (lane == 0) wsum[wv] = acc;
    __syncthreads();
    if (threadIdx.x == 0) {
        float s = 0.0f;
        #pragma unroll
        for (int w = 0; w < BLOCK / 64; ++w) s += wsum[w];
        partials[blockIdx.x] = s;  // unconditional write every launch (poison-safe)
    }
}

__global__ __launch_bounds__(BLOCK) void kl_final_kernel(
    const float* __restrict__ partials, float* __restrict__ out)
{
    double acc = 0.0;
    for (int i = threadIdx.x; i < GRID1; i += BLOCK) acc += (double)partials[i];
    #pragma unroll
    for (int off = 32; off > 0; off >>= 1) acc += __shfl_down(acc, off, 64);
    __shared__ double wsum[BLOCK / 64];
    const int lane = threadIdx.x & 63;
    const int wv   = threadIdx.x >> 6;
    if (lane == 0) wsum[wv] = acc;
    __syncthreads();
    if (threadIdx.x == 0) {
        double s = 0.0;
        #pragma unroll
        for (int w = 0; w < BLOCK / 64; ++w) s += wsum[w];
        out[0] = (float)(0.5 * s / (double)B_ROWS - 0.5 * (double)N_COLS);
    }
}

extern "C" void kernel_launch(void* const* d_in, const int* in_sizes, int n_in,
                              void* d_out, int out_size, void* d_ws, size_t ws_size,
                              hipStream_t stream) {
    const float4* mu1  = (const float4*)d_in[0];
    const float4* mu2  = (const float4*)d_in[1];
    const float4* sg1  = (const float4*)d_in[2];
    const float4* sg2  = (const float4*)d_in[3];
    const float4* mask = (const float4*)d_in[4];
    float* partials = (float*)d_ws;  // GRID1 floats = 16 KiB scratch
    float* out = (float*)d_out;

    kl_partial_kernel<<<GRID1, BLOCK, 0, stream>>>(mu1, mu2, sg1, sg2, mask, partials);
    kl_final_kernel<<<1, BLOCK, 0, stream>>>(partials, out);
}